// Round 1
// baseline (1395.691 us; speedup 1.0000x reference)
//
#include <hip/hip_runtime.h>

// MultiHeadAttention: b=2, t=2048, E=1024, h=16, d=64, fp32.
// Round 1: correct fp32 baseline.
//   K1: qkv = x @ W_qkv^T, scattered into q/k/v [b,h,t,d]  (col = dd*48 + which*16 + h)
//   K2: flash-style fp32 attention -> AO [b,t,E]  (already merged 'b h t d -> b t (h d)')
//   K3: out = AO @ W_out^T
// Workspace: qkv 3*4194304 floats + AO 4194304 floats = 64 MiB.

#define HEADS 16
#define EMB   1024
#define HDIM  64
#define BB    2
#define TT    2048

// ---------------------------------------------------------------------------
// Tiled fp32 GEMM: C = A[M,K] @ W[N,K]^T.  BM=BN=128, BK=16, 256 threads,
// 8x8 micro-tile per thread arranged as four 4x4 quadrants (rows tm..tm+3 and
// tm+64..tm+67 x cols tn..tn+3 and tn+64..tn+67) so LDS reads are <=2-way.
// SCATTER=1: C is the qkv workspace; logical col n -> (dd = n/48, which, h).
// ---------------------------------------------------------------------------
template<int SCATTER>
__global__ __launch_bounds__(256)
void gemm_xwt(const float* __restrict__ A, const float* __restrict__ W,
              float* __restrict__ C, int M, int N, int K) {
    __shared__ float As[16][128];
    __shared__ float Bs[16][128];
    const int tid = threadIdx.x;
    const int m0 = blockIdx.y * 128;
    const int n0 = blockIdx.x * 128;
    const int tm = ((tid >> 4) & 15) * 4;   // 0..60
    const int tn = (tid & 15) * 4;          // 0..60
    const int lr = tid >> 1;                // 0..127
    const int lc = (tid & 1) * 8;           // 0 or 8

    float acc[2][2][4][4];
    #pragma unroll
    for (int a = 0; a < 2; ++a)
        #pragma unroll
        for (int b = 0; b < 2; ++b)
            #pragma unroll
            for (int i = 0; i < 4; ++i)
                #pragma unroll
                for (int j = 0; j < 4; ++j)
                    acc[a][b][i][j] = 0.f;

    const float* Ap = A + (size_t)(m0 + lr) * K + lc;
    const float* Wp = W + (size_t)(n0 + lr) * K + lc;

    for (int k0 = 0; k0 < K; k0 += 16) {
        const float4 av0 = *(const float4*)(Ap + k0);
        const float4 av1 = *(const float4*)(Ap + k0 + 4);
        const float4 wv0 = *(const float4*)(Wp + k0);
        const float4 wv1 = *(const float4*)(Wp + k0 + 4);
        __syncthreads();
        As[lc+0][lr]=av0.x; As[lc+1][lr]=av0.y; As[lc+2][lr]=av0.z; As[lc+3][lr]=av0.w;
        As[lc+4][lr]=av1.x; As[lc+5][lr]=av1.y; As[lc+6][lr]=av1.z; As[lc+7][lr]=av1.w;
        Bs[lc+0][lr]=wv0.x; Bs[lc+1][lr]=wv0.y; Bs[lc+2][lr]=wv0.z; Bs[lc+3][lr]=wv0.w;
        Bs[lc+4][lr]=wv1.x; Bs[lc+5][lr]=wv1.y; Bs[lc+6][lr]=wv1.z; Bs[lc+7][lr]=wv1.w;
        __syncthreads();
        #pragma unroll
        for (int kk = 0; kk < 16; ++kk) {
            const float4 a0 = *(const float4*)&As[kk][tm];
            const float4 a1 = *(const float4*)&As[kk][tm + 64];
            const float4 b0 = *(const float4*)&Bs[kk][tn];
            const float4 b1 = *(const float4*)&Bs[kk][tn + 64];
            const float ar[2][4] = {{a0.x,a0.y,a0.z,a0.w},{a1.x,a1.y,a1.z,a1.w}};
            const float br[2][4] = {{b0.x,b0.y,b0.z,b0.w},{b1.x,b1.y,b1.z,b1.w}};
            #pragma unroll
            for (int rh = 0; rh < 2; ++rh)
                #pragma unroll
                for (int i = 0; i < 4; ++i)
                    #pragma unroll
                    for (int ch = 0; ch < 2; ++ch)
                        #pragma unroll
                        for (int j = 0; j < 4; ++j)
                            acc[rh][ch][i][j] = fmaf(ar[rh][i], br[ch][j], acc[rh][ch][i][j]);
        }
    }

    if (SCATTER) {
        const size_t BHTD = (size_t)BB * HEADS * TT * HDIM;
        #pragma unroll
        for (int rh = 0; rh < 2; ++rh)
            #pragma unroll
            for (int i = 0; i < 4; ++i) {
                const int m  = m0 + tm + rh * 64 + i;
                const int bb = m >> 11;       // /2048
                const int tt = m & 2047;
                #pragma unroll
                for (int ch = 0; ch < 2; ++ch)
                    #pragma unroll
                    for (int j = 0; j < 4; ++j) {
                        const int n     = n0 + tn + ch * 64 + j;
                        const int dd    = n / 48;
                        const int r     = n - dd * 48;
                        const int which = r >> 4;
                        const int hh    = r & 15;
                        C[(size_t)which * BHTD +
                          (((size_t)bb * HEADS + hh) * TT + tt) * HDIM + dd] =
                            acc[rh][ch][i][j];
                    }
            }
    } else {
        #pragma unroll
        for (int rh = 0; rh < 2; ++rh)
            #pragma unroll
            for (int i = 0; i < 4; ++i) {
                const int m = m0 + tm + rh * 64 + i;
                #pragma unroll
                for (int ch = 0; ch < 2; ++ch) {
                    float4 v;
                    v.x = acc[rh][ch][i][0]; v.y = acc[rh][ch][i][1];
                    v.z = acc[rh][ch][i][2]; v.w = acc[rh][ch][i][3];
                    *(float4*)&C[(size_t)m * N + n0 + tn + ch * 64] = v;
                }
            }
    }
}

// ---------------------------------------------------------------------------
// Flash-style fp32 attention. Block = (b, h, 64 query rows), 256 threads.
// Thread (row = tid/4, quad = tid&3) owns q-row in regs (pre-scaled by 1/8),
// 16 of 64 score columns (j = quad + 4*jj, interleaved to dodge LDS bank
// conflicts), and dims [quad*16, quad*16+16) of the output row.
// ---------------------------------------------------------------------------
__global__ __launch_bounds__(256)
void attn_fp32(const float* __restrict__ qkv, float* __restrict__ AO) {
    __shared__ float Ps[64][68];   // P tile (scores -> probs)
    __shared__ float Ks[64][68];
    __shared__ float Vs[64][68];
    const int tid = threadIdx.x;
    const int i0  = blockIdx.x * 64;
    const int h   = blockIdx.y;
    const int b   = blockIdx.z;
    const size_t BHTD = (size_t)BB * HEADS * TT * HDIM;
    const float* Qb = qkv + (size_t)(b * HEADS + h) * TT * HDIM;
    const float* Kb = Qb + BHTD;
    const float* Vb = Qb + 2 * BHTD;

    const int row  = tid >> 2;   // 0..63
    const int quad = tid & 3;    // 0..3
    const int ldc  = quad * 16;

    float q[64];
    {
        const float* qr = Qb + (size_t)(i0 + row) * HDIM;
        #pragma unroll
        for (int c = 0; c < 16; ++c) {
            const float4 v = *(const float4*)(qr + 4 * c);
            q[4*c+0] = v.x * 0.125f;
            q[4*c+1] = v.y * 0.125f;
            q[4*c+2] = v.z * 0.125f;
            q[4*c+3] = v.w * 0.125f;
        }
    }
    float o[16];
    #pragma unroll
    for (int i = 0; i < 16; ++i) o[i] = 0.f;
    float mrun = -1e30f, lrun = 0.f;

    for (int jt = 0; jt < TT / 64; ++jt) {
        __syncthreads();   // protect Ks/Vs from previous iteration's readers
        const float* kr = Kb + (size_t)(jt * 64 + row) * HDIM + ldc;
        const float* vr = Vb + (size_t)(jt * 64 + row) * HDIM + ldc;
        #pragma unroll
        for (int c = 0; c < 4; ++c) {
            *(float4*)&Ks[row][ldc + 4*c] = *(const float4*)(kr + 4*c);
            *(float4*)&Vs[row][ldc + 4*c] = *(const float4*)(vr + 4*c);
        }
        __syncthreads();

        // S = (Q/8) @ K^T for this thread's 16 interleaved columns
        float s[16];
        #pragma unroll
        for (int jj = 0; jj < 16; ++jj) {
            const int j = quad + 4 * jj;
            float a0 = 0.f, a1 = 0.f, a2 = 0.f, a3 = 0.f;
            #pragma unroll
            for (int c = 0; c < 16; ++c) {
                const float4 kv = *(const float4*)&Ks[j][4 * c];
                a0 = fmaf(q[4*c+0], kv.x, a0);
                a1 = fmaf(q[4*c+1], kv.y, a1);
                a2 = fmaf(q[4*c+2], kv.z, a2);
                a3 = fmaf(q[4*c+3], kv.w, a3);
            }
            s[jj] = (a0 + a1) + (a2 + a3);
        }

        // online softmax: row stats across the 4 quad lanes (same wave)
        float mloc = s[0];
        #pragma unroll
        for (int jj = 1; jj < 16; ++jj) mloc = fmaxf(mloc, s[jj]);
        mloc = fmaxf(mloc, __shfl_xor(mloc, 1));
        mloc = fmaxf(mloc, __shfl_xor(mloc, 2));
        const float mnew = fmaxf(mrun, mloc);
        const float corr = __expf(mrun - mnew);
        float p[16];
        float lloc = 0.f;
        #pragma unroll
        for (int jj = 0; jj < 16; ++jj) { p[jj] = __expf(s[jj] - mnew); lloc += p[jj]; }
        lloc += __shfl_xor(lloc, 1);
        lloc += __shfl_xor(lloc, 2);
        lrun = lrun * corr + lloc;
        mrun = mnew;
        #pragma unroll
        for (int i = 0; i < 16; ++i) o[i] *= corr;
        #pragma unroll
        for (int jj = 0; jj < 16; ++jj) Ps[row][quad + 4 * jj] = p[jj];
        __syncthreads();

        // O += P @ V   (thread accumulates its 16 dims over all 64 keys)
        #pragma unroll
        for (int j = 0; j < 64; ++j) {
            const float pv = Ps[row][j];
            #pragma unroll
            for (int c = 0; c < 4; ++c) {
                const float4 v4 = *(const float4*)&Vs[j][ldc + 4 * c];
                o[4*c+0] = fmaf(pv, v4.x, o[4*c+0]);
                o[4*c+1] = fmaf(pv, v4.y, o[4*c+1]);
                o[4*c+2] = fmaf(pv, v4.z, o[4*c+2]);
                o[4*c+3] = fmaf(pv, v4.w, o[4*c+3]);
            }
        }
    }

    const float inv = 1.0f / lrun;
    float* orow = AO + ((size_t)b * TT + i0 + row) * EMB + h * HDIM + ldc;
    #pragma unroll
    for (int c = 0; c < 4; ++c) {
        float4 v;
        v.x = o[4*c+0] * inv; v.y = o[4*c+1] * inv;
        v.z = o[4*c+2] * inv; v.w = o[4*c+3] * inv;
        *(float4*)(orow + 4 * c) = v;
    }
}

// ---------------------------------------------------------------------------
extern "C" void kernel_launch(void* const* d_in, const int* in_sizes, int n_in,
                              void* d_out, int out_size, void* d_ws, size_t ws_size,
                              hipStream_t stream) {
    const float* x    = (const float*)d_in[0];   // [2,2048,1024]
    const float* Wqkv = (const float*)d_in[1];   // [3072,1024]
    const float* Wout = (const float*)d_in[2];   // [1024,1024]
    float* out = (float*)d_out;                  // [2,2048,1024]

    const size_t BHTD = (size_t)BB * HEADS * TT * HDIM;   // 4194304
    float* qkv = (float*)d_ws;           // 3*BHTD floats (q,k,v in [b,h,t,d])
    float* AO  = qkv + 3 * BHTD;         // [b,t,E] attention output

    const int M = BB * TT;               // 4096

    dim3 g1((3 * EMB) / 128, M / 128);   // 24 x 32
    gemm_xwt<1><<<g1, dim3(256), 0, stream>>>(x, Wqkv, qkv, M, 3 * EMB, EMB);

    dim3 g2(TT / 64, HEADS, BB);         // 32 x 16 x 2
    attn_fp32<<<g2, dim3(256), 0, stream>>>(qkv, AO);

    dim3 g3(EMB / 128, M / 128);         // 8 x 32
    gemm_xwt<0><<<g3, dim3(256), 0, stream>>>(AO, Wout, out, M, EMB, EMB);
}

// Round 2
// 314.272 us; speedup vs baseline: 4.4410x; 4.4410x over previous
//
#include <hip/hip_runtime.h>
#include <hip/hip_bf16.h>

// MHA b=2 t=2048 E=1024 h=16 d=64 (fp32 in/out).
// R2: MFMA bf16 pipeline.
//   split_hilo : W_qkv, W_out -> hi/lo bf16 planes (hi=bf16(w), lo=bf16(w-hi))
//   gemm_hilo<1>: qkv = x @ Wqkv^T via 3-MFMA hi/lo; scatter epilogue writes
//                 Q,K bf16 [b,h,t,d] and V bf16 TRANSPOSED [b,h,d,t]
//   attn_mfma  : flash attention, 16x16x32 bf16 MFMA, swapped QK^T, fp32 softmax
//   gemm_hilo<0>: out = AO @ Wout^T (AO fp32 from attention)
// ws: Wqkv hi/lo 12MB + Wout hi/lo 4MB + Q/K/V bf16 25MB + AO fp32 16MB = 56MB.

#define HEADS 16
#define EMB   1024
#define HDIM  64
#define BB    2
#define TT    2048
#define KD    1024

typedef __attribute__((ext_vector_type(8))) short bf16x8;
typedef __attribute__((ext_vector_type(4))) float f32x4;

__device__ __forceinline__ unsigned short f2bf(float f) {
    __hip_bfloat16 h = __float2bfloat16(f);
    return __builtin_bit_cast(unsigned short, h);
}
__device__ __forceinline__ float bf2f(unsigned short u) {
    unsigned v = (unsigned)u << 16;
    return __builtin_bit_cast(float, v);
}
__device__ __forceinline__ unsigned pk2(float a, float b) {
    return (unsigned)f2bf(a) | ((unsigned)f2bf(b) << 16);
}

// ---------------------------------------------------------------------------
__global__ __launch_bounds__(256)
void split_hilo(const float* __restrict__ src, unsigned short* __restrict__ hi,
                unsigned short* __restrict__ lo, int n4) {
    int i = blockIdx.x * 256 + threadIdx.x;
    if (i >= n4) return;
    const float4 v = ((const float4*)src)[i];
    ushort4 h, l;
    h.x = f2bf(v.x); l.x = f2bf(v.x - bf2f(h.x));
    h.y = f2bf(v.y); l.y = f2bf(v.y - bf2f(h.y));
    h.z = f2bf(v.z); l.z = f2bf(v.z - bf2f(h.z));
    h.w = f2bf(v.w); l.w = f2bf(v.w - bf2f(h.w));
    ((ushort4*)hi)[i] = h;
    ((ushort4*)lo)[i] = l;
}

// ---------------------------------------------------------------------------
// C = A[M,1024] @ W[N,1024]^T.  128x128 tile, BK=32, 256 thr (4 waves 2x2),
// per wave 4x4 frags of 16x16x32.  A fp32 -> hi/lo bf16 in-kernel; W planes
// pre-split.  acc = ah*wh + ah*wl + al*wh (lo*lo dropped).
// LDS rows padded to 40 elems (80B) -> <=2-way bank aliasing on ds_read_b128.
// ---------------------------------------------------------------------------
template<int SCATTER>
__global__ __launch_bounds__(256)
void gemm_hilo(const float* __restrict__ A,
               const unsigned short* __restrict__ Whi,
               const unsigned short* __restrict__ Wlo,
               float* __restrict__ Cout,
               unsigned short* __restrict__ Qp,
               unsigned short* __restrict__ Kp,
               unsigned short* __restrict__ Vp) {
    __shared__ __align__(16) unsigned short Ah[128][40];
    __shared__ __align__(16) unsigned short Al[128][40];
    __shared__ __align__(16) unsigned short Wh[128][40];
    __shared__ __align__(16) unsigned short Wl[128][40];

    const int tid  = threadIdx.x;
    const int lane = tid & 63;
    const int w    = tid >> 6;
    const int n0   = blockIdx.x * 128;
    const int m0   = blockIdx.y * 128;
    const int wr   = (w >> 1) * 64;
    const int wc   = (w & 1) * 64;
    const int r16  = lane & 15;
    const int g8   = (lane >> 4) * 8;

    const int srow = tid >> 1;          // 0..127
    const int skof = (tid & 1) * 16;    // 0 / 16

    const float*          Asrc = A   + (size_t)(m0 + srow) * KD + skof;
    const unsigned short* Whs  = Whi + (size_t)(n0 + srow) * KD + skof;
    const unsigned short* Wls  = Wlo + (size_t)(n0 + srow) * KD + skof;

    f32x4 acc[4][4];
    #pragma unroll
    for (int i = 0; i < 4; ++i)
        #pragma unroll
        for (int j = 0; j < 4; ++j)
            acc[i][j] = (f32x4){0.f, 0.f, 0.f, 0.f};

    float4 a4[4];
    bf16x8 wh8[2], wl8[2];

#define GLOADS(K0)                                                     \
    do {                                                               \
        a4[0]  = *(const float4*)(Asrc + (K0));                        \
        a4[1]  = *(const float4*)(Asrc + (K0) + 4);                    \
        a4[2]  = *(const float4*)(Asrc + (K0) + 8);                    \
        a4[3]  = *(const float4*)(Asrc + (K0) + 12);                   \
        wh8[0] = *(const bf16x8*)(Whs + (K0));                         \
        wh8[1] = *(const bf16x8*)(Whs + (K0) + 8);                     \
        wl8[0] = *(const bf16x8*)(Wls + (K0));                         \
        wl8[1] = *(const bf16x8*)(Wls + (K0) + 8);                     \
    } while (0)

    GLOADS(0);

    for (int ks = 0; ks < 32; ++ks) {
        __syncthreads();
        {   // convert A fp32 -> hi/lo and write all staged data to LDS
            float av[16];
            #pragma unroll
            for (int q = 0; q < 4; ++q) {
                av[4*q+0] = a4[q].x; av[4*q+1] = a4[q].y;
                av[4*q+2] = a4[q].z; av[4*q+3] = a4[q].w;
            }
            union { bf16x8 v; unsigned short u[8]; } h0, h1, l0, l1;
            #pragma unroll
            for (int j = 0; j < 8; ++j) {
                const unsigned short hb = f2bf(av[j]);
                h0.u[j] = hb; l0.u[j] = f2bf(av[j] - bf2f(hb));
            }
            #pragma unroll
            for (int j = 0; j < 8; ++j) {
                const unsigned short hb = f2bf(av[8 + j]);
                h1.u[j] = hb; l1.u[j] = f2bf(av[8 + j] - bf2f(hb));
            }
            *(bf16x8*)&Ah[srow][skof]     = h0.v;
            *(bf16x8*)&Ah[srow][skof + 8] = h1.v;
            *(bf16x8*)&Al[srow][skof]     = l0.v;
            *(bf16x8*)&Al[srow][skof + 8] = l1.v;
            *(bf16x8*)&Wh[srow][skof]     = wh8[0];
            *(bf16x8*)&Wh[srow][skof + 8] = wh8[1];
            *(bf16x8*)&Wl[srow][skof]     = wl8[0];
            *(bf16x8*)&Wl[srow][skof + 8] = wl8[1];
        }
        __syncthreads();
        if (ks < 31) GLOADS((ks + 1) * 32);

        bf16x8 bh[4], bl[4];
        #pragma unroll
        for (int ni = 0; ni < 4; ++ni) {
            const int r = wc + ni * 16 + r16;
            bh[ni] = *(const bf16x8*)&Wh[r][g8];
            bl[ni] = *(const bf16x8*)&Wl[r][g8];
        }
        #pragma unroll
        for (int mi = 0; mi < 4; ++mi) {
            const int r = wr + mi * 16 + r16;
            const bf16x8 ah = *(const bf16x8*)&Ah[r][g8];
            const bf16x8 al = *(const bf16x8*)&Al[r][g8];
            #pragma unroll
            for (int ni = 0; ni < 4; ++ni) {
                acc[mi][ni] = __builtin_amdgcn_mfma_f32_16x16x32_bf16(ah, bh[ni], acc[mi][ni], 0, 0, 0);
                acc[mi][ni] = __builtin_amdgcn_mfma_f32_16x16x32_bf16(ah, bl[ni], acc[mi][ni], 0, 0, 0);
                acc[mi][ni] = __builtin_amdgcn_mfma_f32_16x16x32_bf16(al, bh[ni], acc[mi][ni], 0, 0, 0);
            }
        }
    }
#undef GLOADS

    if (SCATTER) {
        // col n -> dd = n/48, which = (n%48)/16, hh = n%16.  Frag col-base is
        // 16-aligned => which/dd uniform per frag, hh = lane&15.
        #pragma unroll
        for (int ni = 0; ni < 4; ++ni) {
            const int nb    = n0 + wc + ni * 16;
            const int which = (nb % 48) >> 4;
            const int dd    = nb / 48;
            const int hh    = r16;
            #pragma unroll
            for (int mi = 0; mi < 4; ++mi) {
                #pragma unroll
                for (int j = 0; j < 4; ++j) {
                    const int m  = m0 + wr + mi * 16 + (lane >> 4) * 4 + j;
                    const int bb = m >> 11, tt = m & 2047;
                    const unsigned short bf = f2bf(acc[mi][ni][j]);
                    if (which == 0)
                        Qp[(((size_t)(bb * HEADS + hh)) * TT + tt) * HDIM + dd] = bf;
                    else if (which == 1)
                        Kp[(((size_t)(bb * HEADS + hh)) * TT + tt) * HDIM + dd] = bf;
                    else
                        Vp[(((size_t)(bb * HEADS + hh)) * HDIM + dd) * TT + tt] = bf;
                }
            }
        }
    } else {
        #pragma unroll
        for (int mi = 0; mi < 4; ++mi)
            #pragma unroll
            for (int j = 0; j < 4; ++j) {
                const int m = m0 + wr + mi * 16 + (lane >> 4) * 4 + j;
                #pragma unroll
                for (int ni = 0; ni < 4; ++ni)
                    Cout[(size_t)m * EMB + n0 + wc + ni * 16 + r16] = acc[mi][ni][j];
            }
    }
}

// ---------------------------------------------------------------------------
// Flash attention, bf16 MFMA.  Block = (qt, h, b): 64 q-rows, 4 waves (16 q
// rows each).  Swapped QK^T: S^T = mfma(K_frag, Q_frag) so each lane holds a
// full 64-key slice of ONE q-row (q = lane&15) -> softmax reduce = 2 shfl_xor.
// P -> bf16 -> per-wave LDS tile -> PV A-frags; V staged as [d][key] (from the
// pre-transposed [b,h,d,t] plane) so PV B-frags are contiguous ds_read_b128.
// ---------------------------------------------------------------------------
__global__ __launch_bounds__(256)
void attn_mfma(const unsigned short* __restrict__ Qb,
               const unsigned short* __restrict__ Kb,
               const unsigned short* __restrict__ Vt,
               float* __restrict__ AO) {
    __shared__ __align__(16) unsigned short Ks[64][72];
    __shared__ __align__(16) unsigned short Vs[64][72];
    __shared__ __align__(16) unsigned short Pl[4][16][72];

    const int tid = threadIdx.x, lane = tid & 63, w = tid >> 6;
    const int qt = blockIdx.x, h = blockIdx.y, b = blockIdx.z;
    const int bh = b * HEADS + h;
    const unsigned short* Qsrc = Qb + (size_t)bh * TT * HDIM;
    const unsigned short* Ksrc = Kb + (size_t)bh * TT * HDIM;
    const unsigned short* Vsrc = Vt + (size_t)bh * HDIM * TT;

    const int r16 = lane & 15, g = lane >> 4;

    bf16x8 qf0, qf1;
    {
        const size_t q = (size_t)(qt * 64 + w * 16 + r16);
        qf0 = *(const bf16x8*)(Qsrc + q * HDIM + g * 8);
        qf1 = *(const bf16x8*)(Qsrc + q * HDIM + g * 8 + 32);
    }

    f32x4 o[4];
    #pragma unroll
    for (int c = 0; c < 4; ++c) o[c] = (f32x4){0.f, 0.f, 0.f, 0.f};
    float mrun = -1e30f, lrun = 0.f;

    const int srow = tid >> 2;          // 0..63
    const int scol = (tid & 3) * 16;    // 16-elem (32B) chunks

    bf16x8 kst0, kst1, vst0, vst1;
#define LOADKV(J0)                                                               \
    do {                                                                         \
        kst0 = *(const bf16x8*)(Ksrc + (size_t)((J0) + srow) * HDIM + scol);     \
        kst1 = *(const bf16x8*)(Ksrc + (size_t)((J0) + srow) * HDIM + scol + 8); \
        vst0 = *(const bf16x8*)(Vsrc + (size_t)srow * TT + (J0) + scol);         \
        vst1 = *(const bf16x8*)(Vsrc + (size_t)srow * TT + (J0) + scol + 8);     \
    } while (0)

    LOADKV(0);

    for (int jt = 0; jt < 32; ++jt) {
        __syncthreads();
        *(bf16x8*)&Ks[srow][scol]     = kst0;
        *(bf16x8*)&Ks[srow][scol + 8] = kst1;
        *(bf16x8*)&Vs[srow][scol]     = vst0;
        *(bf16x8*)&Vs[srow][scol + 8] = vst1;
        __syncthreads();
        if (jt < 31) LOADKV((jt + 1) * 64);

        // S^T[key][q] = sum_d K[key][d] Q[q][d]
        f32x4 st[4];
        #pragma unroll
        for (int kt = 0; kt < 4; ++kt) st[kt] = (f32x4){0.f, 0.f, 0.f, 0.f};
        #pragma unroll
        for (int kt = 0; kt < 4; ++kt) {
            const bf16x8 ka0 = *(const bf16x8*)&Ks[kt * 16 + r16][g * 8];
            const bf16x8 ka1 = *(const bf16x8*)&Ks[kt * 16 + r16][g * 8 + 32];
            st[kt] = __builtin_amdgcn_mfma_f32_16x16x32_bf16(ka0, qf0, st[kt], 0, 0, 0);
            st[kt] = __builtin_amdgcn_mfma_f32_16x16x32_bf16(ka1, qf1, st[kt], 0, 0, 0);
        }

        // online softmax for q-row (lane&15); 4 lane-copies (g) reduced by shfl
        float p[4][4];
        float pmax = -1e30f;
        #pragma unroll
        for (int kt = 0; kt < 4; ++kt)
            #pragma unroll
            for (int j = 0; j < 4; ++j) {
                const float s = st[kt][j] * 0.125f;
                p[kt][j] = s;
                pmax = fmaxf(pmax, s);
            }
        pmax = fmaxf(pmax, __shfl_xor(pmax, 16));
        pmax = fmaxf(pmax, __shfl_xor(pmax, 32));
        const float mnew = fmaxf(mrun, pmax);
        const float corr = __expf(mrun - mnew);
        float psum = 0.f;
        #pragma unroll
        for (int kt = 0; kt < 4; ++kt)
            #pragma unroll
            for (int j = 0; j < 4; ++j) {
                p[kt][j] = __expf(p[kt][j] - mnew);
                psum += p[kt][j];
            }
        psum += __shfl_xor(psum, 16);
        psum += __shfl_xor(psum, 32);
        lrun = lrun * corr + psum;
        mrun = mnew;

        // rescale O (O-frag rows are q-local 4g+j; corr lives at lane q-local)
        float cj[4];
        #pragma unroll
        for (int j = 0; j < 4; ++j) cj[j] = __shfl(corr, g * 4 + j);
        #pragma unroll
        for (int c = 0; c < 4; ++c)
            #pragma unroll
            for (int j = 0; j < 4; ++j) o[c][j] *= cj[j];

        // P (bf16) -> per-wave LDS: row = q-local, cols = keys 16*kt + 4g + j
        #pragma unroll
        for (int kt = 0; kt < 4; ++kt) {
            uint2 uu;
            uu.x = pk2(p[kt][0], p[kt][1]);
            uu.y = pk2(p[kt][2], p[kt][3]);
            *(uint2*)&Pl[w][r16][kt * 16 + g * 4] = uu;
        }

        // O += P @ V
        const bf16x8 pa0 = *(const bf16x8*)&Pl[w][r16][g * 8];
        const bf16x8 pa1 = *(const bf16x8*)&Pl[w][r16][g * 8 + 32];
        #pragma unroll
        for (int c = 0; c < 4; ++c) {
            const bf16x8 vb0 = *(const bf16x8*)&Vs[c * 16 + r16][g * 8];
            const bf16x8 vb1 = *(const bf16x8*)&Vs[c * 16 + r16][g * 8 + 32];
            o[c] = __builtin_amdgcn_mfma_f32_16x16x32_bf16(pa0, vb0, o[c], 0, 0, 0);
            o[c] = __builtin_amdgcn_mfma_f32_16x16x32_bf16(pa1, vb1, o[c], 0, 0, 0);
        }
    }
#undef LOADKV

    const float invl = 1.0f / lrun;
    float ij[4];
    #pragma unroll
    for (int j = 0; j < 4; ++j) ij[j] = __shfl(invl, g * 4 + j);
    #pragma unroll
    for (int c = 0; c < 4; ++c)
        #pragma unroll
        for (int j = 0; j < 4; ++j) {
            const int q = qt * 64 + w * 16 + g * 4 + j;
            AO[((size_t)b * TT + q) * EMB + h * HDIM + c * 16 + r16] = o[c][j] * ij[j];
        }
}

// ---------------------------------------------------------------------------
extern "C" void kernel_launch(void* const* d_in, const int* in_sizes, int n_in,
                              void* d_out, int out_size, void* d_ws, size_t ws_size,
                              hipStream_t stream) {
    const float* x    = (const float*)d_in[0];   // [2,2048,1024]
    const float* Wqkv = (const float*)d_in[1];   // [3072,1024]
    const float* Wout = (const float*)d_in[2];   // [1024,1024]
    float* out = (float*)d_out;

    unsigned short* Wqh = (unsigned short*)d_ws;           // 3145728
    unsigned short* Wql = Wqh + 3145728;                   // 3145728
    unsigned short* Woh = Wql + 3145728;                   // 1048576
    unsigned short* Wol = Woh + 1048576;                   // 1048576
    unsigned short* Qb  = Wol + 1048576;                   // 4194304
    unsigned short* Kb  = Qb  + 4194304;                   // 4194304
    unsigned short* Vt  = Kb  + 4194304;                   // 4194304 ([b,h,d,t])
    float*          AO  = (float*)(Vt + 4194304);          // 4194304 fp32

    split_hilo<<<3072, 256, 0, stream>>>(Wqkv, Wqh, Wql, 786432);
    split_hilo<<<1024, 256, 0, stream>>>(Wout, Woh, Wol, 262144);

    gemm_hilo<1><<<dim3(24, 32), 256, 0, stream>>>(x, Wqh, Wql, nullptr, Qb, Kb, Vt);

    attn_mfma<<<dim3(32, 16, 2), 256, 0, stream>>>(Qb, Kb, Vt, AO);

    gemm_hilo<0><<<dim3(8, 32), 256, 0, stream>>>(AO, Woh, Wol, out,
                                                  nullptr, nullptr, nullptr);
}

// Round 3
// 188.707 us; speedup vs baseline: 7.3961x; 1.6654x over previous
//
#include <hip/hip_runtime.h>
#include <hip/hip_bf16.h>

// MHA b=2 t=2048 E=1024 h=16 d=64 (fp32 in/out).
// R3: fix QKV-GEMM write amplification (356MB -> ~30MB) via W-row permutation
//     (output col n' = which*1024 + h*64 + d) + swapped-operand MFMA (D[n][m],
//     lane holds 4 consecutive n) -> packed coalesced stores.
//     2-term hi/lo (A_hi*W_hi + A_hi*W_lo): W at ~fp24, A at bf16.
//   conv_bf16   : x fp32 -> xb bf16
//   split_w<1>  : W_qkv -> permuted hi/lo bf16 planes
//   split_w<0>  : W_out -> hi/lo bf16 planes
//   gemm_w2<1>  : QK -> QKb [b,t,2048] bf16 row-major; V -> Vt [b,h,d,t] bf16
//   attn_mfma   : flash attention (16x16x32 bf16, swapped QK^T) -> AOb bf16
//   gemm_w2<0>  : out = AOb @ Wout^T (fp32, float4 stores)

#define HEADS 16
#define EMB   1024
#define HDIM  64
#define BB    2
#define TT    2048

typedef __attribute__((ext_vector_type(8))) short bf16x8;
typedef __attribute__((ext_vector_type(4))) float f32x4;

__device__ __forceinline__ unsigned short f2bf(float f) {
    __hip_bfloat16 h = __float2bfloat16(f);
    return __builtin_bit_cast(unsigned short, h);
}
__device__ __forceinline__ float bf2f(unsigned short u) {
    unsigned v = (unsigned)u << 16;
    return __builtin_bit_cast(float, v);
}
__device__ __forceinline__ unsigned pk2(float a, float b) {
    return (unsigned)f2bf(a) | ((unsigned)f2bf(b) << 16);
}

// ---------------------------------------------------------------------------
__global__ __launch_bounds__(256)
void conv_bf16(const float* __restrict__ src, unsigned short* __restrict__ dst,
               int n8) {
    int i = blockIdx.x * 256 + threadIdx.x;
    if (i >= n8) return;
    const float4 v0 = ((const float4*)src)[i * 2];
    const float4 v1 = ((const float4*)src)[i * 2 + 1];
    ushort4 a, b;
    a.x = f2bf(v0.x); a.y = f2bf(v0.y); a.z = f2bf(v0.z); a.w = f2bf(v0.w);
    b.x = f2bf(v1.x); b.y = f2bf(v1.y); b.z = f2bf(v1.z); b.w = f2bf(v1.w);
    ((ushort4*)dst)[i * 2]     = a;
    ((ushort4*)dst)[i * 2 + 1] = b;
}

// ---------------------------------------------------------------------------
// One block per destination row n'.  PERM=1: src row = d*48 + which*16 + h
// where n' = which*1024 + h*64 + d (so GEMM emits [t][which,h,d] directly).
// ---------------------------------------------------------------------------
template<int PERM>
__global__ __launch_bounds__(256)
void split_w(const float* __restrict__ src, unsigned short* __restrict__ hi,
             unsigned short* __restrict__ lo) {
    const int np = blockIdx.x;
    int ns;
    if (PERM) {
        const int d = np & 63, h = (np >> 6) & 15, k = np >> 10;
        ns = d * 48 + k * 16 + h;
    } else {
        ns = np;
    }
    const float4 v = ((const float4*)(src + (size_t)ns * 1024))[threadIdx.x];
    ushort4 hh, ll;
    hh.x = f2bf(v.x); ll.x = f2bf(v.x - bf2f(hh.x));
    hh.y = f2bf(v.y); ll.y = f2bf(v.y - bf2f(hh.y));
    hh.z = f2bf(v.z); ll.z = f2bf(v.z - bf2f(hh.z));
    hh.w = f2bf(v.w); ll.w = f2bf(v.w - bf2f(hh.w));
    ((ushort4*)(hi + (size_t)np * 1024))[threadIdx.x] = hh;
    ((ushort4*)(lo + (size_t)np * 1024))[threadIdx.x] = ll;
}

// ---------------------------------------------------------------------------
// C^T-style GEMM: D[n][m] = sum_k W[n,k] * A[m,k], A bf16 [M][1024], W hi/lo
// bf16 [N][1024].  128x128 tile, BK=32, 4 waves (2n x 2m), 4x4 frags of
// 16x16x32, 2 MFMA per frag (hi+lo).  Lane holds 4 consecutive n per frag.
// EPI=0: Cout fp32 [m][Cn] float4 stores.
// EPI=1: n0<2048 -> QKb bf16 [m][2048] ushort4; n0>=2048 -> Vt [b,h,d,t] u16.
// ---------------------------------------------------------------------------
template<int EPI>
__global__ __launch_bounds__(256)
void gemm_w2(const unsigned short* __restrict__ Ag,
             const unsigned short* __restrict__ Whg,
             const unsigned short* __restrict__ Wlg,
             float* __restrict__ Cout, int Cn,
             unsigned short* __restrict__ QKb,
             unsigned short* __restrict__ Vt) {
    __shared__ __align__(16) unsigned short Ab[128 * 40];
    __shared__ __align__(16) unsigned short Wh[128 * 40];
    __shared__ __align__(16) unsigned short Wl[128 * 40];

    const int tid = threadIdx.x, lane = tid & 63, w = tid >> 6;
    const int n0 = blockIdx.x * 128, m0 = blockIdx.y * 128;
    const int wn = (w >> 1) * 64, wm = (w & 1) * 64;
    const int r16 = lane & 15, g8 = (lane >> 4) * 8, gq = (lane >> 4) * 4;

    const int srow = tid >> 1, skof = (tid & 1) * 16;
    const unsigned short* As  = Ag  + (size_t)(m0 + srow) * 1024 + skof;
    const unsigned short* Whs = Whg + (size_t)(n0 + srow) * 1024 + skof;
    const unsigned short* Wls = Wlg + (size_t)(n0 + srow) * 1024 + skof;

    f32x4 acc[4][4];  // [ni][mi]
    #pragma unroll
    for (int i = 0; i < 4; ++i)
        #pragma unroll
        for (int j = 0; j < 4; ++j)
            acc[i][j] = (f32x4){0.f, 0.f, 0.f, 0.f};

    bf16x8 a8[2], h8[2], l8[2];
#define GL(K0)                                         \
    do {                                               \
        a8[0] = *(const bf16x8*)(As  + (K0));          \
        a8[1] = *(const bf16x8*)(As  + (K0) + 8);      \
        h8[0] = *(const bf16x8*)(Whs + (K0));          \
        h8[1] = *(const bf16x8*)(Whs + (K0) + 8);      \
        l8[0] = *(const bf16x8*)(Wls + (K0));          \
        l8[1] = *(const bf16x8*)(Wls + (K0) + 8);      \
    } while (0)

    GL(0);

    for (int ks = 0; ks < 32; ++ks) {
        __syncthreads();
        *(bf16x8*)&Ab[srow * 40 + skof]     = a8[0];
        *(bf16x8*)&Ab[srow * 40 + skof + 8] = a8[1];
        *(bf16x8*)&Wh[srow * 40 + skof]     = h8[0];
        *(bf16x8*)&Wh[srow * 40 + skof + 8] = h8[1];
        *(bf16x8*)&Wl[srow * 40 + skof]     = l8[0];
        *(bf16x8*)&Wl[srow * 40 + skof + 8] = l8[1];
        __syncthreads();
        if (ks < 31) GL((ks + 1) * 32);

        bf16x8 xf[4];
        #pragma unroll
        for (int mi = 0; mi < 4; ++mi)
            xf[mi] = *(const bf16x8*)&Ab[(wm + mi * 16 + r16) * 40 + g8];
        #pragma unroll
        for (int ni = 0; ni < 4; ++ni) {
            const bf16x8 hf = *(const bf16x8*)&Wh[(wn + ni * 16 + r16) * 40 + g8];
            const bf16x8 lf = *(const bf16x8*)&Wl[(wn + ni * 16 + r16) * 40 + g8];
            #pragma unroll
            for (int mi = 0; mi < 4; ++mi) {
                acc[ni][mi] = __builtin_amdgcn_mfma_f32_16x16x32_bf16(hf, xf[mi], acc[ni][mi], 0, 0, 0);
                acc[ni][mi] = __builtin_amdgcn_mfma_f32_16x16x32_bf16(lf, xf[mi], acc[ni][mi], 0, 0, 0);
            }
        }
    }
#undef GL

    if (EPI == 0) {
        #pragma unroll
        for (int ni = 0; ni < 4; ++ni)
            #pragma unroll
            for (int mi = 0; mi < 4; ++mi) {
                const int m = m0 + wm + mi * 16 + r16;
                *(f32x4*)&Cout[(size_t)m * Cn + (n0 + wn + ni * 16 + gq)] = acc[ni][mi];
            }
    } else if (n0 < 2048) {
        #pragma unroll
        for (int ni = 0; ni < 4; ++ni)
            #pragma unroll
            for (int mi = 0; mi < 4; ++mi) {
                const int m  = m0 + wm + mi * 16 + r16;
                const int np = n0 + wn + ni * 16 + gq;
                ushort4 u;
                u.x = f2bf(acc[ni][mi][0]); u.y = f2bf(acc[ni][mi][1]);
                u.z = f2bf(acc[ni][mi][2]); u.w = f2bf(acc[ni][mi][3]);
                *(ushort4*)&QKb[(size_t)m * 2048 + np] = u;
            }
    } else {
        const int b = m0 >> 11, t0 = m0 & 2047;
        #pragma unroll
        for (int ni = 0; ni < 4; ++ni)
            #pragma unroll
            for (int mi = 0; mi < 4; ++mi) {
                const int t   = t0 + wm + mi * 16 + r16;
                const int nv0 = (n0 - 2048) + wn + ni * 16 + gq;
                #pragma unroll
                for (int j = 0; j < 4; ++j) {
                    const int nv = nv0 + j, h = nv >> 6, d = nv & 63;
                    Vt[(((size_t)(b * HEADS + h)) * HDIM + d) * TT + t] =
                        f2bf(acc[ni][mi][j]);
                }
            }
    }
}

// ---------------------------------------------------------------------------
// Flash attention, bf16 MFMA (verified R2 structure).  Q/K from QKb
// [b,t,2048] (q cols 0..1023, k cols 1024..2047, per head h*64+d); V from
// Vt [b,h,d,t].  Swapped QK^T: S^T = mfma(K,Q).  Output AOb bf16 [b,t,E].
// ---------------------------------------------------------------------------
__global__ __launch_bounds__(256)
void attn_mfma(const unsigned short* __restrict__ QKb,
               const unsigned short* __restrict__ Vt,
               unsigned short* __restrict__ AOb) {
    __shared__ __align__(16) unsigned short Ks[64][72];
    __shared__ __align__(16) unsigned short Vs[64][72];
    __shared__ __align__(16) unsigned short Pl[4][16][72];

    const int tid = threadIdx.x, lane = tid & 63, w = tid >> 6;
    const int qt = blockIdx.x, h = blockIdx.y, b = blockIdx.z;
    const unsigned short* Vsrc = Vt + (size_t)(b * HEADS + h) * HDIM * TT;

    const int r16 = lane & 15, g = lane >> 4;

    bf16x8 qf0, qf1;
    {
        const size_t base =
            ((size_t)(b * TT + qt * 64 + w * 16 + r16)) * 2048 + h * HDIM;
        qf0 = *(const bf16x8*)(QKb + base + g * 8);
        qf1 = *(const bf16x8*)(QKb + base + g * 8 + 32);
    }

    f32x4 o[4];
    #pragma unroll
    for (int c = 0; c < 4; ++c) o[c] = (f32x4){0.f, 0.f, 0.f, 0.f};
    float mrun = -1e30f, lrun = 0.f;

    const int srow = tid >> 2;          // 0..63
    const int scol = (tid & 3) * 16;

    bf16x8 kst0, kst1, vst0, vst1;
#define LOADKV(J0)                                                              \
    do {                                                                        \
        const size_t kb =                                                       \
            ((size_t)(b * TT + (J0) + srow)) * 2048 + 1024 + h * HDIM + scol;   \
        kst0 = *(const bf16x8*)(QKb + kb);                                      \
        kst1 = *(const bf16x8*)(QKb + kb + 8);                                  \
        vst0 = *(const bf16x8*)(Vsrc + (size_t)srow * TT + (J0) + scol);        \
        vst1 = *(const bf16x8*)(Vsrc + (size_t)srow * TT + (J0) + scol + 8);    \
    } while (0)

    LOADKV(0);

    for (int jt = 0; jt < 32; ++jt) {
        __syncthreads();
        *(bf16x8*)&Ks[srow][scol]     = kst0;
        *(bf16x8*)&Ks[srow][scol + 8] = kst1;
        *(bf16x8*)&Vs[srow][scol]     = vst0;
        *(bf16x8*)&Vs[srow][scol + 8] = vst1;
        __syncthreads();
        if (jt < 31) LOADKV((jt + 1) * 64);

        // S^T[key][q]
        f32x4 st[4];
        #pragma unroll
        for (int kt = 0; kt < 4; ++kt) st[kt] = (f32x4){0.f, 0.f, 0.f, 0.f};
        #pragma unroll
        for (int kt = 0; kt < 4; ++kt) {
            const bf16x8 ka0 = *(const bf16x8*)&Ks[kt * 16 + r16][g * 8];
            const bf16x8 ka1 = *(const bf16x8*)&Ks[kt * 16 + r16][g * 8 + 32];
            st[kt] = __builtin_amdgcn_mfma_f32_16x16x32_bf16(ka0, qf0, st[kt], 0, 0, 0);
            st[kt] = __builtin_amdgcn_mfma_f32_16x16x32_bf16(ka1, qf1, st[kt], 0, 0, 0);
        }

        // online softmax (q-row = lane&15; reduce over g-copies via shfl)
        float p[4][4];
        float pmax = -1e30f;
        #pragma unroll
        for (int kt = 0; kt < 4; ++kt)
            #pragma unroll
            for (int j = 0; j < 4; ++j) {
                const float s = st[kt][j] * 0.125f;
                p[kt][j] = s;
                pmax = fmaxf(pmax, s);
            }
        pmax = fmaxf(pmax, __shfl_xor(pmax, 16));
        pmax = fmaxf(pmax, __shfl_xor(pmax, 32));
        const float mnew = fmaxf(mrun, pmax);
        const float corr = __expf(mrun - mnew);
        float psum = 0.f;
        #pragma unroll
        for (int kt = 0; kt < 4; ++kt)
            #pragma unroll
            for (int j = 0; j < 4; ++j) {
                p[kt][j] = __expf(p[kt][j] - mnew);
                psum += p[kt][j];
            }
        psum += __shfl_xor(psum, 16);
        psum += __shfl_xor(psum, 32);
        lrun = lrun * corr + psum;
        mrun = mnew;

        float cj[4];
        #pragma unroll
        for (int j = 0; j < 4; ++j) cj[j] = __shfl(corr, g * 4 + j);
        #pragma unroll
        for (int c = 0; c < 4; ++c)
            #pragma unroll
            for (int j = 0; j < 4; ++j) o[c][j] *= cj[j];

        #pragma unroll
        for (int kt = 0; kt < 4; ++kt) {
            uint2 uu;
            uu.x = pk2(p[kt][0], p[kt][1]);
            uu.y = pk2(p[kt][2], p[kt][3]);
            *(uint2*)&Pl[w][r16][kt * 16 + g * 4] = uu;
        }

        const bf16x8 pa0 = *(const bf16x8*)&Pl[w][r16][g * 8];
        const bf16x8 pa1 = *(const bf16x8*)&Pl[w][r16][g * 8 + 32];
        #pragma unroll
        for (int c = 0; c < 4; ++c) {
            const bf16x8 vb0 = *(const bf16x8*)&Vs[c * 16 + r16][g * 8];
            const bf16x8 vb1 = *(const bf16x8*)&Vs[c * 16 + r16][g * 8 + 32];
            o[c] = __builtin_amdgcn_mfma_f32_16x16x32_bf16(pa0, vb0, o[c], 0, 0, 0);
            o[c] = __builtin_amdgcn_mfma_f32_16x16x32_bf16(pa1, vb1, o[c], 0, 0, 0);
        }
    }
#undef LOADKV

    const float invl = 1.0f / lrun;
    float ij[4];
    #pragma unroll
    for (int j = 0; j < 4; ++j) ij[j] = __shfl(invl, g * 4 + j);
    #pragma unroll
    for (int c = 0; c < 4; ++c)
        #pragma unroll
        for (int j = 0; j < 4; ++j) {
            const int q = qt * 64 + w * 16 + g * 4 + j;
            AOb[((size_t)(b * TT + q)) * EMB + h * HDIM + c * 16 + r16] =
                f2bf(o[c][j] * ij[j]);
        }
}

// ---------------------------------------------------------------------------
extern "C" void kernel_launch(void* const* d_in, const int* in_sizes, int n_in,
                              void* d_out, int out_size, void* d_ws, size_t ws_size,
                              hipStream_t stream) {
    const float* x    = (const float*)d_in[0];   // [2,2048,1024]
    const float* Wqkv = (const float*)d_in[1];   // [3072,1024]
    const float* Wout = (const float*)d_in[2];   // [1024,1024]
    float* out = (float*)d_out;

    unsigned short* Wqh = (unsigned short*)d_ws;   // 3145728
    unsigned short* Wql = Wqh + 3145728;
    unsigned short* Woh = Wql + 3145728;           // 1048576
    unsigned short* Wol = Woh + 1048576;
    unsigned short* xb  = Wol + 1048576;           // 4194304
    unsigned short* QKb = xb  + 4194304;           // 8388608 [b,t,2048]
    unsigned short* Vt  = QKb + 8388608;           // 4194304 [b,h,d,t]
    unsigned short* AOb = Vt  + 4194304;           // 4194304 [b,t,1024]

    conv_bf16<<<2048, 256, 0, stream>>>(x, xb, 524288);
    split_w<1><<<3072, 256, 0, stream>>>(Wqkv, Wqh, Wql);
    split_w<0><<<1024, 256, 0, stream>>>(Wout, Woh, Wol);

    gemm_w2<1><<<dim3(24, 32), 256, 0, stream>>>(xb, Wqh, Wql,
                                                 nullptr, 0, QKb, Vt);

    attn_mfma<<<dim3(32, 16, 2), 256, 0, stream>>>(QKb, Vt, AOb);

    gemm_w2<0><<<dim3(8, 32), 256, 0, stream>>>(AOb, Woh, Wol,
                                                out, 1024, nullptr, nullptr);
}

// Round 4
// 144.348 us; speedup vs baseline: 9.6689x; 1.3073x over previous
//
#include <hip/hip_runtime.h>
#include <hip/hip_bf16.h>

// MHA b=2 t=2048 E=1024 h=16 d=64 (fp32 in/out).
// R4: attn VALU diet (exp2 domain, perm-pack P, defer-max) + T2 XOR-swizzled
//     LDS everywhere + global_load_lds staging (pre-swizzled global source,
//     linear LDS dest) for both GEMMs and attention K/V.
//     GEMMs single bf16 MFMA (no hi/lo): error budget ~2e-3 < 4.94e-3.
// Q is pre-scaled by 0.125*log2(e) in the QKV epilogue -> softmax in exp2.

#define HEADS 16
#define EMB   1024
#define HDIM  64
#define BB    2
#define TT    2048
#define QSCALE 0.18033688011112042f   // (1/8) * log2(e)

typedef __attribute__((ext_vector_type(8))) short bf16x8;
typedef __attribute__((ext_vector_type(4))) float f32x4;

__device__ __forceinline__ unsigned short f2bf(float f) {
    __hip_bfloat16 h = __float2bfloat16(f);
    return __builtin_bit_cast(unsigned short, h);
}
__device__ __forceinline__ float fexp2(float x) {
#if __has_builtin(__builtin_amdgcn_exp2f)
    return __builtin_amdgcn_exp2f(x);
#else
    return exp2f(x);
#endif
}
// pack {bf16_trunc(x), bf16_trunc(y)} -> u32 (x in low half), 1 instr
__device__ __forceinline__ unsigned pk2t(float x, float y) {
#if __has_builtin(__builtin_amdgcn_perm)
    return __builtin_amdgcn_perm(__builtin_bit_cast(unsigned, y),
                                 __builtin_bit_cast(unsigned, x), 0x07060302u);
#else
    return (__builtin_bit_cast(unsigned, x) >> 16) |
           (__builtin_bit_cast(unsigned, y) & 0xffff0000u);
#endif
}
__device__ __forceinline__ void gload_lds16(const void* g, void* l) {
    __builtin_amdgcn_global_load_lds(
        (const __attribute__((address_space(1))) void*)g,
        (__attribute__((address_space(3))) void*)l, 16, 0, 0);
}
// swizzled ushort index into a [rows][64]-short LDS tile (128B rows, 16B blks)
__device__ __forceinline__ int swzi(int row, int blk) {
    return row * 64 + ((blk ^ (row & 7)) << 3);
}

// ---------------------------------------------------------------------------
__global__ __launch_bounds__(256)
void conv_bf16(const float* __restrict__ src, unsigned short* __restrict__ dst,
               int n8) {
    int i = blockIdx.x * 256 + threadIdx.x;
    if (i >= n8) return;
    const float4 v0 = ((const float4*)src)[i * 2];
    const float4 v1 = ((const float4*)src)[i * 2 + 1];
    ushort4 a, b;
    a.x = f2bf(v0.x); a.y = f2bf(v0.y); a.z = f2bf(v0.z); a.w = f2bf(v0.w);
    b.x = f2bf(v1.x); b.y = f2bf(v1.y); b.z = f2bf(v1.z); b.w = f2bf(v1.w);
    ((ushort4*)dst)[i * 2]     = a;
    ((ushort4*)dst)[i * 2 + 1] = b;
}

// W conversion; PERM=1 permutes rows so output col n' = which*1024 + h*64 + d.
template<int PERM>
__global__ __launch_bounds__(256)
void convw(const float* __restrict__ src, unsigned short* __restrict__ dst) {
    const int np = blockIdx.x;
    const int ns = PERM ? ((np & 63) * 48 + (np >> 10) * 16 + ((np >> 6) & 15))
                        : np;
    const float4 v = ((const float4*)(src + (size_t)ns * 1024))[threadIdx.x];
    ushort4 u;
    u.x = f2bf(v.x); u.y = f2bf(v.y); u.z = f2bf(v.z); u.w = f2bf(v.w);
    ((ushort4*)(dst + (size_t)np * 1024))[threadIdx.x] = u;
}

// ---------------------------------------------------------------------------
// D[n][m] GEMM: A bf16 [M][1024], W bf16 [N][1024].  128x128 tile, BK=64,
// 4 waves (2n x 2m), 4x4 frags 16x16x32.  Staging: global_load_lds 16B with
// inverse-swizzled source, linear LDS; reads apply the XOR swizzle.
// EPI=0: Cout fp32 [m][1024].  EPI=1: n<1024 Q(*QSCALE), n<2048 K -> QKb
// bf16 [b*t][2048]; n>=2048 V -> Vt bf16 [b,h,d,t].
// ---------------------------------------------------------------------------
template<int EPI>
__global__ __launch_bounds__(256)
void gemm_bf16(const unsigned short* __restrict__ Ag,
               const unsigned short* __restrict__ Wg,
               float* __restrict__ Cout,
               unsigned short* __restrict__ QKb,
               unsigned short* __restrict__ Vt) {
    __shared__ __align__(16) unsigned short Ab[128 * 64];
    __shared__ __align__(16) unsigned short Wb[128 * 64];

    const int tid = threadIdx.x, lane = tid & 63, w = tid >> 6;
    const int n0 = blockIdx.x * 128, m0 = blockIdx.y * 128;
    const int wn = (w >> 1) * 64, wm = (w & 1) * 64;
    const int r16 = lane & 15, g = lane >> 4;

    f32x4 acc[4][4];  // [ni][mi]
    #pragma unroll
    for (int i = 0; i < 4; ++i)
        #pragma unroll
        for (int j = 0; j < 4; ++j)
            acc[i][j] = (f32x4){0.f, 0.f, 0.f, 0.f};

    // stage helpers: wave w fills rows [w*32, w*32+32) of each array
    const int srl = lane >> 3;          // 0..7 row-in-instr
    const int scb = lane & 7;           // dest 16B block

    for (int kt = 0; kt < 16; ++kt) {
        __syncthreads();
        const int k0 = kt * 64;
        #pragma unroll
        for (int i = 0; i < 4; ++i) {
            const int row = w * 32 + i * 8 + srl;
            const int cbs = (scb ^ (row & 7)) << 3;   // src col (shorts)
            gload_lds16(Ag + (size_t)(m0 + row) * 1024 + k0 + cbs,
                        Ab + (size_t)(w * 32 + i * 8) * 64);
            gload_lds16(Wg + (size_t)(n0 + row) * 1024 + k0 + cbs,
                        Wb + (size_t)(w * 32 + i * 8) * 64);
        }
        __syncthreads();

        #pragma unroll
        for (int ks = 0; ks < 2; ++ks) {
            bf16x8 xf[4];
            #pragma unroll
            for (int mi = 0; mi < 4; ++mi)
                xf[mi] = *(const bf16x8*)&Ab[swzi(wm + mi * 16 + r16, ks * 4 + g)];
            #pragma unroll
            for (int ni = 0; ni < 4; ++ni) {
                const bf16x8 wf = *(const bf16x8*)&Wb[swzi(wn + ni * 16 + r16, ks * 4 + g)];
                #pragma unroll
                for (int mi = 0; mi < 4; ++mi)
                    acc[ni][mi] = __builtin_amdgcn_mfma_f32_16x16x32_bf16(
                        wf, xf[mi], acc[ni][mi], 0, 0, 0);
            }
        }
    }

    const int gq = g * 4;
    if (EPI == 0) {
        #pragma unroll
        for (int ni = 0; ni < 4; ++ni)
            #pragma unroll
            for (int mi = 0; mi < 4; ++mi) {
                const int m = m0 + wm + mi * 16 + r16;
                *(f32x4*)&Cout[(size_t)m * 1024 + (n0 + wn + ni * 16 + gq)] =
                    acc[ni][mi];
            }
    } else if (n0 < 2048) {
        #pragma unroll
        for (int ni = 0; ni < 4; ++ni) {
            const float qs = (n0 + wn + ni * 16) < 1024 ? QSCALE : 1.0f;
            #pragma unroll
            for (int mi = 0; mi < 4; ++mi) {
                const int m  = m0 + wm + mi * 16 + r16;
                const int np = n0 + wn + ni * 16 + gq;
                ushort4 u;
                u.x = f2bf(acc[ni][mi][0] * qs); u.y = f2bf(acc[ni][mi][1] * qs);
                u.z = f2bf(acc[ni][mi][2] * qs); u.w = f2bf(acc[ni][mi][3] * qs);
                *(ushort4*)&QKb[(size_t)m * 2048 + np] = u;
            }
        }
    } else {
        const int b = m0 >> 11, t0 = m0 & 2047;
        #pragma unroll
        for (int ni = 0; ni < 4; ++ni)
            #pragma unroll
            for (int mi = 0; mi < 4; ++mi) {
                const int t   = t0 + wm + mi * 16 + r16;
                const int nv0 = (n0 - 2048) + wn + ni * 16 + gq;
                #pragma unroll
                for (int j = 0; j < 4; ++j) {
                    const int nv = nv0 + j, h = nv >> 6, d = nv & 63;
                    Vt[(((size_t)(b * HEADS + h)) * HDIM + d) * TT + t] =
                        f2bf(acc[ni][mi][j]);
                }
            }
    }
}

// ---------------------------------------------------------------------------
// Flash attention, bf16 MFMA, exp2-domain softmax (Q pre-scaled).
// Block = 64 q-rows, 4 waves x 16 rows.  K/V double-buffered swizzled LDS via
// global_load_lds (pre-swizzled source).  Swapped QK^T; P truncate-packed to
// per-wave swizzled LDS tile; defer-max rescale (THR=11.5 in log2 units).
// ---------------------------------------------------------------------------
__global__ __launch_bounds__(256)
void attn_mfma(const unsigned short* __restrict__ QKb,
               const unsigned short* __restrict__ Vt,
               unsigned short* __restrict__ AOb) {
    __shared__ __align__(16) unsigned short Ks[2][64 * 64];
    __shared__ __align__(16) unsigned short Vs[2][64 * 64];
    __shared__ __align__(16) unsigned short Pl[4][16 * 64];

    const int tid = threadIdx.x, lane = tid & 63, w = tid >> 6;
    const int qt = blockIdx.x, h = blockIdx.y, b = blockIdx.z;
    const unsigned short* Vsrc = Vt + (size_t)(b * HEADS + h) * HDIM * TT;

    const int r16 = lane & 15, g = lane >> 4;
    const int srl = lane >> 3;          // stage row-in-instr 0..7
    const int scb = lane & 7;           // stage dest block

    bf16x8 qf0, qf1;
    {
        const size_t base =
            ((size_t)(b * TT + qt * 64 + w * 16 + r16)) * 2048 + h * HDIM;
        qf0 = *(const bf16x8*)(QKb + base + g * 8);
        qf1 = *(const bf16x8*)(QKb + base + g * 8 + 32);
    }

    f32x4 o[4];
    #pragma unroll
    for (int c = 0; c < 4; ++c) o[c] = (f32x4){0.f, 0.f, 0.f, 0.f};
    float mrun = -1e30f, lrun = 0.f;

#define STAGEKV(BUF, J0)                                                        \
    do {                                                                        \
        _Pragma("unroll")                                                       \
        for (int i = 0; i < 2; ++i) {                                           \
            const int rl  = w * 16 + i * 8 + srl;                               \
            const int cbs = (scb ^ (rl & 7)) << 3;                              \
            gload_lds16(QKb + (size_t)(b * TT + (J0) + rl) * 2048 + 1024 +      \
                            h * HDIM + cbs,                                     \
                        &Ks[BUF][(w * 16 + i * 8) * 64]);                       \
            gload_lds16(Vsrc + (size_t)rl * TT + (J0) + cbs,                    \
                        &Vs[BUF][(w * 16 + i * 8) * 64]);                       \
        }                                                                       \
    } while (0)

    STAGEKV(0, 0);

    for (int jt = 0; jt < 32; ++jt) {
        const int bb = jt & 1;
        __syncthreads();                       // drains staging for tile jt
        if (jt < 31) STAGEKV(bb ^ 1, (jt + 1) * 64);

        // S^T[key][q], already in log2 units (Q pre-scaled)
        f32x4 st[4];
        #pragma unroll
        for (int kt = 0; kt < 4; ++kt) st[kt] = (f32x4){0.f, 0.f, 0.f, 0.f};
        __builtin_amdgcn_s_setprio(1);
        #pragma unroll
        for (int kt = 0; kt < 4; ++kt) {
            const bf16x8 ka0 = *(const bf16x8*)&Ks[bb][swzi(kt * 16 + r16, g)];
            const bf16x8 ka1 = *(const bf16x8*)&Ks[bb][swzi(kt * 16 + r16, g + 4)];
            st[kt] = __builtin_amdgcn_mfma_f32_16x16x32_bf16(ka0, qf0, st[kt], 0, 0, 0);
            st[kt] = __builtin_amdgcn_mfma_f32_16x16x32_bf16(ka1, qf1, st[kt], 0, 0, 0);
        }
        __builtin_amdgcn_s_setprio(0);

        // row max across this lane's 16 scores + the 4 g-copies
        float pmax = st[0][0];
        #pragma unroll
        for (int kt = 0; kt < 4; ++kt)
            #pragma unroll
            for (int j = 0; j < 4; ++j) pmax = fmaxf(pmax, st[kt][j]);
        pmax = fmaxf(pmax, __shfl_xor(pmax, 16));
        pmax = fmaxf(pmax, __shfl_xor(pmax, 32));

        // defer-max: only rescale when the max moved materially (T13)
        if (!__all(pmax <= mrun + 11.5f)) {
            const float mnew = fmaxf(mrun, pmax);
            const float corr = fexp2(mrun - mnew);
            float cj[4];
            #pragma unroll
            for (int j = 0; j < 4; ++j) cj[j] = __shfl(corr, g * 4 + j);
            #pragma unroll
            for (int c = 0; c < 4; ++c)
                #pragma unroll
                for (int j = 0; j < 4; ++j) o[c][j] *= cj[j];
            lrun *= corr;
            mrun = mnew;
        }

        float p[4][4];
        float psum = 0.f;
        #pragma unroll
        for (int kt = 0; kt < 4; ++kt)
            #pragma unroll
            for (int j = 0; j < 4; ++j) {
                p[kt][j] = fexp2(st[kt][j] - mrun);
                psum += p[kt][j];
            }
        psum += __shfl_xor(psum, 16);
        psum += __shfl_xor(psum, 32);
        lrun += psum;

        // P -> bf16 (truncate-pack) -> per-wave swizzled LDS tile
        #pragma unroll
        for (int kt = 0; kt < 4; ++kt) {
            const int bw  = kt * 2 + (g >> 1);
            const int idx = r16 * 64 + ((bw ^ (r16 & 7)) << 3) + (g & 1) * 4;
            uint2 uu;
            uu.x = pk2t(p[kt][0], p[kt][1]);
            uu.y = pk2t(p[kt][2], p[kt][3]);
            *(uint2*)&Pl[w][idx] = uu;
        }

        // O += P @ V
        const bf16x8 pa0 = *(const bf16x8*)&Pl[w][swzi(r16, g)];
        const bf16x8 pa1 = *(const bf16x8*)&Pl[w][swzi(r16, g + 4)];
        __builtin_amdgcn_s_setprio(1);
        #pragma unroll
        for (int c = 0; c < 4; ++c) {
            const bf16x8 vb0 = *(const bf16x8*)&Vs[bb][swzi(c * 16 + r16, g)];
            const bf16x8 vb1 = *(const bf16x8*)&Vs[bb][swzi(c * 16 + r16, g + 4)];
            o[c] = __builtin_amdgcn_mfma_f32_16x16x32_bf16(pa0, vb0, o[c], 0, 0, 0);
            o[c] = __builtin_amdgcn_mfma_f32_16x16x32_bf16(pa1, vb1, o[c], 0, 0, 0);
        }
        __builtin_amdgcn_s_setprio(0);
    }
#undef STAGEKV

    const float invl = 1.0f / lrun;
    float ij[4];
    #pragma unroll
    for (int j = 0; j < 4; ++j) ij[j] = __shfl(invl, g * 4 + j);
    #pragma unroll
    for (int c = 0; c < 4; ++c)
        #pragma unroll
        for (int j = 0; j < 4; ++j) {
            const int q = qt * 64 + w * 16 + g * 4 + j;
            AOb[((size_t)(b * TT + q)) * EMB + h * HDIM + c * 16 + r16] =
                f2bf(o[c][j] * ij[j]);
        }
}

// ---------------------------------------------------------------------------
extern "C" void kernel_launch(void* const* d_in, const int* in_sizes, int n_in,
                              void* d_out, int out_size, void* d_ws, size_t ws_size,
                              hipStream_t stream) {
    const float* x    = (const float*)d_in[0];   // [2,2048,1024]
    const float* Wqkv = (const float*)d_in[1];   // [3072,1024]
    const float* Wout = (const float*)d_in[2];   // [1024,1024]
    float* out = (float*)d_out;

    unsigned short* Wqb = (unsigned short*)d_ws;   // 3145728 (permuted)
    unsigned short* Wob = Wqb + 3145728;           // 1048576
    unsigned short* xb  = Wob + 1048576;           // 4194304
    unsigned short* QKb = xb  + 4194304;           // 8388608 [b*t][2048]
    unsigned short* Vt  = QKb + 8388608;           // 4194304 [b,h,d,t]
    unsigned short* AOb = Vt  + 4194304;           // 4194304 [b*t][1024]

    conv_bf16<<<2048, 256, 0, stream>>>(x, xb, 524288);
    convw<1><<<3072, 256, 0, stream>>>(Wqkv, Wqb);
    convw<0><<<1024, 256, 0, stream>>>(Wout, Wob);

    gemm_bf16<1><<<dim3(24, 32), 256, 0, stream>>>(xb, Wqb, nullptr, QKb, Vt);

    attn_mfma<<<dim3(32, 16, 2), 256, 0, stream>>>(QKb, Vt, AOb);

    gemm_bf16<0><<<dim3(8, 32), 256, 0, stream>>>(AOb, Wob, out, nullptr, nullptr);
}

// Round 6
// 140.029 us; speedup vs baseline: 9.9672x; 1.0308x over previous
//
#include <hip/hip_runtime.h>
#include <hip/hip_bf16.h>

// MHA b=2 t=2048 E=1024 h=16 d=64 (fp32 in/out).
// R6 (= R5 with compile fixes): attention on 32x32x16 MFMA.
//   - 128 q/block, 4 waves x 32 q; K/V double-buffered swizzled LDS via
//     global_load_lds (pre-swizzled per-lane source, linear dest).
//   - swapped QK^T (bf16): lane holds 32 scores of q-row (lane&31).
//   - subtract-free exp2 softmax (guarded offset path for pathological data).
//   - P -> fp16 in-register via cvt_pkrtz + v_permlane32_swap_b32 (no P LDS).
//   - PV in fp16 MFMA (V stored fp16 [b,h,d,t] by the QKV epilogue).
// GEMMs: R4 structure (BK=64, global_load_lds, XOR-swizzled reads), bf16.

#define HEADS 16
#define EMB   1024
#define HDIM  64
#define BB    2
#define TT    2048
#define QSCALE 0.18033688011112042f   // (1/8) * log2(e)

typedef __attribute__((ext_vector_type(8)))  short      bf16x8;
typedef __attribute__((ext_vector_type(8)))  _Float16   f16x8;
typedef __attribute__((ext_vector_type(4)))  float      f32x4;
typedef __attribute__((ext_vector_type(16))) float      f32x16;
typedef __attribute__((ext_vector_type(4)))  unsigned   u32x4;

__device__ __forceinline__ unsigned short f2bf(float f) {
    __hip_bfloat16 h = __float2bfloat16(f);
    return __builtin_bit_cast(unsigned short, h);
}
__device__ __forceinline__ float fexp2(float x) {
#if __has_builtin(__builtin_amdgcn_exp2f)
    return __builtin_amdgcn_exp2f(x);
#else
    return exp2f(x);
#endif
}
// pack {fp16(a), fp16(b)} -> u32 via v_cvt_pkrtz_f16_f32 (1 instr)
__device__ __forceinline__ unsigned pkrtz(float a, float b) {
    auto r = __builtin_amdgcn_cvt_pkrtz(a, b);
    return __builtin_bit_cast(unsigned, r);
}
// fp32 -> fp16 bits (RTZ), low half of a pkrtz
__device__ __forceinline__ unsigned short f2h(float f) {
    return (unsigned short)(pkrtz(f, 0.f) & 0xffffu);
}
__device__ __forceinline__ void gload_lds16(const void* g, void* l) {
    __builtin_amdgcn_global_load_lds(
        (const __attribute__((address_space(1))) void*)g,
        (__attribute__((address_space(3))) void*)l, 16, 0, 0);
}
// swizzled ushort index into [rows][64]-short LDS tile (128B rows, 16B blocks)
__device__ __forceinline__ int swzi(int row, int blk) {
    return row * 64 + ((blk ^ (row & 7)) << 3);
}
// v_permlane32_swap_b32: a' = {a.lo32, b.lo32}, b' = {a.hi32, b.hi32}
__device__ __forceinline__ void pl32swap(unsigned& a, unsigned& b) {
    asm("v_permlane32_swap_b32 %0, %1" : "+v"(a), "+v"(b));
}

// ---------------------------------------------------------------------------
__global__ __launch_bounds__(256)
void conv_bf16(const float* __restrict__ src, unsigned short* __restrict__ dst,
               int n8) {
    int i = blockIdx.x * 256 + threadIdx.x;
    if (i >= n8) return;
    const float4 v0 = ((const float4*)src)[i * 2];
    const float4 v1 = ((const float4*)src)[i * 2 + 1];
    ushort4 a, b;
    a.x = f2bf(v0.x); a.y = f2bf(v0.y); a.z = f2bf(v0.z); a.w = f2bf(v0.w);
    b.x = f2bf(v1.x); b.y = f2bf(v1.y); b.z = f2bf(v1.z); b.w = f2bf(v1.w);
    ((ushort4*)dst)[i * 2]     = a;
    ((ushort4*)dst)[i * 2 + 1] = b;
}

// W conversion; PERM=1 permutes rows so output col n' = which*1024 + h*64 + d.
template<int PERM>
__global__ __launch_bounds__(256)
void convw(const float* __restrict__ src, unsigned short* __restrict__ dst) {
    const int np = blockIdx.x;
    const int ns = PERM ? ((np & 63) * 48 + (np >> 10) * 16 + ((np >> 6) & 15))
                        : np;
    const float4 v = ((const float4*)(src + (size_t)ns * 1024))[threadIdx.x];
    ushort4 u;
    u.x = f2bf(v.x); u.y = f2bf(v.y); u.z = f2bf(v.z); u.w = f2bf(v.w);
    ((ushort4*)(dst + (size_t)np * 1024))[threadIdx.x] = u;
}

// ---------------------------------------------------------------------------
// D[n][m] GEMM: A bf16 [M][1024], W bf16 [N][1024].  128x128 tile, BK=64,
// 4 waves (2n x 2m), 4x4 frags 16x16x32.  global_load_lds staging.
// EPI=0: Cout fp32 [m][1024].  EPI=1: n<1024 Q(*QSCALE), n<2048 K -> QKb
// bf16 [b*t][2048]; n>=2048 V -> Vt fp16 [b,h,d,t].
// ---------------------------------------------------------------------------
template<int EPI>
__global__ __launch_bounds__(256)
void gemm_bf16(const unsigned short* __restrict__ Ag,
               const unsigned short* __restrict__ Wg,
               float* __restrict__ Cout,
               unsigned short* __restrict__ QKb,
               unsigned short* __restrict__ Vt) {
    __shared__ __align__(16) unsigned short Ab[128 * 64];
    __shared__ __align__(16) unsigned short Wb[128 * 64];

    const int tid = threadIdx.x, lane = tid & 63, w = tid >> 6;
    const int n0 = blockIdx.x * 128, m0 = blockIdx.y * 128;
    const int wn = (w >> 1) * 64, wm = (w & 1) * 64;
    const int r16 = lane & 15, g = lane >> 4;

    f32x4 acc[4][4];  // [ni][mi]
    #pragma unroll
    for (int i = 0; i < 4; ++i)
        #pragma unroll
        for (int j = 0; j < 4; ++j)
            acc[i][j] = (f32x4){0.f, 0.f, 0.f, 0.f};

    const int srl = lane >> 3;          // 0..7 row-in-instr
    const int scb = lane & 7;           // dest 16B block

    for (int kt = 0; kt < 16; ++kt) {
        __syncthreads();
        const int k0 = kt * 64;
        #pragma unroll
        for (int i = 0; i < 4; ++i) {
            const int row = w * 32 + i * 8 + srl;
            const int cbs = (scb ^ (row & 7)) << 3;   // src col (shorts)
            gload_lds16(Ag + (size_t)(m0 + row) * 1024 + k0 + cbs,
                        Ab + (size_t)(w * 32 + i * 8) * 64);
            gload_lds16(Wg + (size_t)(n0 + row) * 1024 + k0 + cbs,
                        Wb + (size_t)(w * 32 + i * 8) * 64);
        }
        __syncthreads();

        #pragma unroll
        for (int ks = 0; ks < 2; ++ks) {
            bf16x8 xf[4];
            #pragma unroll
            for (int mi = 0; mi < 4; ++mi)
                xf[mi] = *(const bf16x8*)&Ab[swzi(wm + mi * 16 + r16, ks * 4 + g)];
            #pragma unroll
            for (int ni = 0; ni < 4; ++ni) {
                const bf16x8 wf = *(const bf16x8*)&Wb[swzi(wn + ni * 16 + r16, ks * 4 + g)];
                #pragma unroll
                for (int mi = 0; mi < 4; ++mi)
                    acc[ni][mi] = __builtin_amdgcn_mfma_f32_16x16x32_bf16(
                        wf, xf[mi], acc[ni][mi], 0, 0, 0);
            }
        }
    }

    const int gq = g * 4;
    if (EPI == 0) {
        #pragma unroll
        for (int ni = 0; ni < 4; ++ni)
            #pragma unroll
            for (int mi = 0; mi < 4; ++mi) {
                const int m = m0 + wm + mi * 16 + r16;
                *(f32x4*)&Cout[(size_t)m * 1024 + (n0 + wn + ni * 16 + gq)] =
                    acc[ni][mi];
            }
    } else if (n0 < 2048) {
        #pragma unroll
        for (int ni = 0; ni < 4; ++ni) {
            const float qs = (n0 + wn + ni * 16) < 1024 ? QSCALE : 1.0f;
            #pragma unroll
            for (int mi = 0; mi < 4; ++mi) {
                const int m  = m0 + wm + mi * 16 + r16;
                const int np = n0 + wn + ni * 16 + gq;
                ushort4 u;
                u.x = f2bf(acc[ni][mi][0] * qs); u.y = f2bf(acc[ni][mi][1] * qs);
                u.z = f2bf(acc[ni][mi][2] * qs); u.w = f2bf(acc[ni][mi][3] * qs);
                *(ushort4*)&QKb[(size_t)m * 2048 + np] = u;
            }
        }
    } else {
        const int b = m0 >> 11, t0 = m0 & 2047;
        #pragma unroll
        for (int ni = 0; ni < 4; ++ni)
            #pragma unroll
            for (int mi = 0; mi < 4; ++mi) {
                const int t   = t0 + wm + mi * 16 + r16;
                const int nv0 = (n0 - 2048) + wn + ni * 16 + gq;
                #pragma unroll
                for (int j = 0; j < 4; ++j) {
                    const int nv = nv0 + j, h = nv >> 6, d = nv & 63;
                    Vt[(((size_t)(b * HEADS + h)) * HDIM + d) * TT + t] =
                        f2h(acc[ni][mi][j]);   // V stored as fp16
                }
            }
    }
}

// ---------------------------------------------------------------------------
// Flash attention, 32x32x16 MFMA.  Block = 128 q (4 waves x 32 q), K/V tile
// 64 keys.  Q bf16 (pre-scaled by QSCALE -> scores in log2 units).
// Swapped QK^T: lane holds, for q = lane&31, keys (reg&3)+8*(reg>>2)+4*hi
// (+32 for st1).  p = exp2(st) (no subtraction; guarded offset path).
// P -> fp16 A-frags fully in-register via cvt_pkrtz + permlane32_swap.
// PV fp16 MFMA from Vs[d][key].
// ---------------------------------------------------------------------------
__global__ __launch_bounds__(256)
void attn32(const unsigned short* __restrict__ QKb,
            const unsigned short* __restrict__ Vt,
            unsigned short* __restrict__ AOb) {
    __shared__ __align__(16) unsigned short Ks[2][64 * 64];
    __shared__ __align__(16) unsigned short Vs[2][64 * 64];

    const int tid = threadIdx.x, lane = tid & 63, w = tid >> 6;
    const int l31 = lane & 31, hi = lane >> 5;
    const int qt = blockIdx.x, h = blockIdx.y, b = blockIdx.z;
    const unsigned short* Vsrc = Vt + (size_t)(b * HEADS + h) * HDIM * TT;

    // Q fragments (B operand): q = l31, d-chunk dc: k = dc*16 + hi*8 + e
    bf16x8 qf[4];
    {
        const unsigned short* qrow =
            QKb + ((size_t)(b * TT + qt * 128 + w * 32 + l31)) * 2048 + h * HDIM;
        #pragma unroll
        for (int dc = 0; dc < 4; ++dc)
            qf[dc] = *(const bf16x8*)(qrow + dc * 16 + hi * 8);
    }

    const f32x16 zz = {};
    f32x16 o0 = {}, o1 = {};
    float lrun = 0.f, m_off = 0.f;
    bool offActive = false;

    const int srl = lane >> 3;   // staging row-in-instr 0..7
    const int scb = lane & 7;    // staging dest 16B block

#define STAGEKV(BUF, J0)                                                         \
    do {                                                                         \
        _Pragma("unroll")                                                        \
        for (int i = 0; i < 2; ++i) {                                            \
            const int rl  = w * 16 + i * 8 + srl;                                \
            const int cbs = (scb ^ (rl & 7)) << 3;                               \
            gload_lds16(QKb + (size_t)(b * TT + (J0) + rl) * 2048 + 1024 +       \
                            h * HDIM + cbs,                                      \
                        &Ks[BUF][(w * 16 + i * 8) * 64]);                        \
            gload_lds16(Vsrc + (size_t)rl * TT + (J0) + cbs,                     \
                        &Vs[BUF][(w * 16 + i * 8) * 64]);                        \
        }                                                                        \
    } while (0)

    STAGEKV(0, 0);

    for (int jt = 0; jt < 32; ++jt) {
        const int bb = jt & 1;
        __syncthreads();                      // staged tile jt ready
        if (jt < 31) STAGEKV(bb ^ 1, (jt + 1) * 64);

        // ---- QK^T: S^T in log2 units -------------------------------------
        f32x16 st0, st1;
        __builtin_amdgcn_s_setprio(1);
        #pragma unroll
        for (int dc = 0; dc < 4; ++dc) {
            const bf16x8 ka0 = *(const bf16x8*)&Ks[bb][swzi(l31,      dc * 2 + hi)];
            const bf16x8 ka1 = *(const bf16x8*)&Ks[bb][swzi(32 + l31, dc * 2 + hi)];
            if (dc == 0) {
                st0 = __builtin_amdgcn_mfma_f32_32x32x16_bf16(ka0, qf[0], zz, 0, 0, 0);
                st1 = __builtin_amdgcn_mfma_f32_32x32x16_bf16(ka1, qf[0], zz, 0, 0, 0);
            } else {
                st0 = __builtin_amdgcn_mfma_f32_32x32x16_bf16(ka0, qf[dc], st0, 0, 0, 0);
                st1 = __builtin_amdgcn_mfma_f32_32x32x16_bf16(ka1, qf[dc], st1, 0, 0, 0);
            }
        }
        __builtin_amdgcn_s_setprio(0);

        // ---- overflow guard (never triggers for sane data) ----------------
        float smax = fmaxf(st0[0], st1[0]);
        #pragma unroll
        for (int j = 1; j < 16; ++j)
            smax = fmaxf(smax, fmaxf(st0[j], st1[j]));
        if (__builtin_expect(offActive || __any(smax > 14.0f), 0)) {
            offActive = true;
            const float rmax = fmaxf(smax, __shfl_xor(smax, 32));
            const float mnew = fmaxf(m_off, rmax);
            const float corr = fexp2(m_off - mnew);
            lrun *= corr;
            #pragma unroll
            for (int r = 0; r < 16; ++r) {
                const int qr = (r & 3) + 8 * (r >> 2) + 4 * hi;
                const float cr = __shfl(corr, qr);
                o0[r] *= cr; o1[r] *= cr;
            }
            m_off = mnew;
            #pragma unroll
            for (int j = 0; j < 16; ++j) { st0[j] -= m_off; st1[j] -= m_off; }
        }

        // ---- exp2 (no subtraction in common path) -------------------------
        float p[32];
        #pragma unroll
        for (int j = 0; j < 16; ++j) {
            p[j]      = fexp2(st0[j]);
            p[16 + j] = fexp2(st1[j]);
        }
        // row-sum (tree); lane partial, combined once at the end
        {
            float t[16];
            #pragma unroll
            for (int j = 0; j < 16; ++j) t[j] = p[j] + p[16 + j];
            #pragma unroll
            for (int j = 0; j < 8; ++j) t[j] += t[j + 8];
            #pragma unroll
            for (int j = 0; j < 4; ++j) t[j] += t[j + 4];
            lrun += (t[0] + t[1]) + (t[2] + t[3]);
        }

        // ---- P -> fp16 A-frags in-register --------------------------------
        unsigned wd[16];
        #pragma unroll
        for (int c = 0; c < 4; ++c) {
            wd[c * 2 + 0]     = pkrtz(p[4 * c + 0],      p[4 * c + 1]);
            wd[c * 2 + 1]     = pkrtz(p[4 * c + 2],      p[4 * c + 3]);
            wd[8 + c * 2 + 0] = pkrtz(p[16 + 4 * c + 0], p[16 + 4 * c + 1]);
            wd[8 + c * 2 + 1] = pkrtz(p[16 + 4 * c + 2], p[16 + 4 * c + 3]);
        }
        f16x8 pa[4];
        #pragma unroll
        for (int f = 0; f < 4; ++f) {
            unsigned w0 = wd[f * 4 + 0], w2 = wd[f * 4 + 2];
            pl32swap(w0, w2);                 // -> frag words 0 and 2
            unsigned w1 = wd[f * 4 + 1], w3 = wd[f * 4 + 3];
            pl32swap(w1, w3);                 // -> frag words 1 and 3
            const u32x4 fv = {w0, w1, w2, w3};
            pa[f] = __builtin_bit_cast(f16x8, fv);
        }

        // ---- O += P @ V (fp16 MFMA, V from Vs[d][key]) ---------------------
        __builtin_amdgcn_s_setprio(1);
        #pragma unroll
        for (int f = 0; f < 4; ++f) {
            const f16x8 vb0 = *(const f16x8*)&Vs[bb][swzi(l31,      f * 2 + hi)];
            const f16x8 vb1 = *(const f16x8*)&Vs[bb][swzi(32 + l31, f * 2 + hi)];
            o0 = __builtin_amdgcn_mfma_f32_32x32x16_f16(pa[f], vb0, o0, 0, 0, 0);
            o1 = __builtin_amdgcn_mfma_f32_32x32x16_f16(pa[f], vb1, o1, 0, 0, 0);
        }
        __builtin_amdgcn_s_setprio(0);
    }
#undef STAGEKV

    // ---- finalize ---------------------------------------------------------
    lrun += __shfl_xor(lrun, 32);
    const float inv = 1.0f / lrun;
    #pragma unroll
    for (int r = 0; r < 16; ++r) {
        const int qr = (r & 3) + 8 * (r >> 2) + 4 * hi;
        const float ir = __shfl(inv, qr);
        const int q = qt * 128 + w * 32 + qr;
        unsigned short* dst = AOb + ((size_t)(b * TT + q)) * EMB + h * HDIM + l31;
        dst[0]  = f2bf(o0[r] * ir);
        dst[32] = f2bf(o1[r] * ir);
    }
}

// ---------------------------------------------------------------------------
extern "C" void kernel_launch(void* const* d_in, const int* in_sizes, int n_in,
                              void* d_out, int out_size, void* d_ws, size_t ws_size,
                              hipStream_t stream) {
    const float* x    = (const float*)d_in[0];   // [2,2048,1024]
    const float* Wqkv = (const float*)d_in[1];   // [3072,1024]
    const float* Wout = (const float*)d_in[2];   // [1024,1024]
    float* out = (float*)d_out;

    unsigned short* Wqb = (unsigned short*)d_ws;   // 3145728 (permuted)
    unsigned short* Wob = Wqb + 3145728;           // 1048576
    unsigned short* xb  = Wob + 1048576;           // 4194304
    unsigned short* QKb = xb  + 4194304;           // 8388608 [b*t][2048]
    unsigned short* Vt  = QKb + 8388608;           // 4194304 [b,h,d,t] fp16
    unsigned short* AOb = Vt  + 4194304;           // 4194304 [b*t][1024]

    conv_bf16<<<2048, 256, 0, stream>>>(x, xb, 524288);
    convw<1><<<3072, 256, 0, stream>>>(Wqkv, Wqb);
    convw<0><<<1024, 256, 0, stream>>>(Wout, Wob);

    gemm_bf16<1><<<dim3(24, 32), 256, 0, stream>>>(xb, Wqb, nullptr, QKb, Vt);

    attn32<<<dim3(16, 16, 2), 256, 0, stream>>>(QKb, Vt, AOb);

    gemm_bf16<0><<<dim3(8, 32), 256, 0, stream>>>(AOb, Wob, out, nullptr, nullptr);
}